// Round 7
// baseline (11005.339 us; speedup 1.0000x reference)
//
#include <hip/hip_runtime.h>
#include <math.h>

// Sinkhorn OT layer, B=8192, C=256, L=100, LAMBD=1.
//
// U = log_u - ||x_i||^2, V = log_v - ||y_j||^2, G[i][j] = 2*dot(x_i,y_j):
//   U[i] = -LSE_j(G[i][j] + V[j]),  V[j] = -LSE_i(G[i][j] + U[i])
// init V[j] = -||y_j||^2. Final: out[i] = y[argmax_j(G[i][j]+V[j])].
//
// d_ws: G only (256 MiB exactly). Small state in __device__ globals, plain
// loads/stores; cross-dispatch visibility via kernel boundaries.
//
// R6 post-mortem: iteration phase sits at exactly 6.3 TB/s (HBM copy
// ceiling) -> zero net MALL benefit. Cause: col grid (1024 blocks) was
// FULLY resident (~2048-block residency), so "descending chunk" order had
// no temporal meaning - instantaneous footprint was all of G.
// R7 experiment: col pass gets a genuine sliding window. RPC=32, 256 chunk
// groups, 8192-block 1D grid, jb fast / chunk DESCENDING slow -> resident
// window ~64 MiB sweeping high->low rows, palindromic against the row
// pass's ascending ~64 MiB window. Pure scheduling change; math identical.

#define B 8192
#define C 256
#define LITERS 100
#define CHUNKS 256                 // column-pass chunk groups
#define RPC (B / CHUNKS)           // 32 rows per chunk

typedef float f32x4 __attribute__((ext_vector_type(4)));

__device__ __align__(16) float g_U[B];
__device__ __align__(16) float g_V[B];
__device__ __align__(16) float g_pm[CHUNKS * B];   // 8 MiB
__device__ __align__(16) float g_ps[CHUNKS * B];   // 8 MiB

// ---------------- init: V[j] = -||y_j||^2 ----------------
__global__ __launch_bounds__(256) void init_V(const float* __restrict__ y) {
    int wave = threadIdx.x >> 6;
    int lane = threadIdx.x & 63;
    int row = blockIdx.x * 4 + wave;
    const f32x4* yr = (const f32x4*)(y + (size_t)row * C);
    f32x4 v = yr[lane];
    float s = v.x * v.x + v.y * v.y + v.z * v.z + v.w * v.w;
    #pragma unroll
    for (int off = 32; off; off >>= 1) s += __shfl_down(s, off, 64);
    if (lane == 0) g_V[row] = -s;
}

// ---------------- GEMM: G = 2 * x @ y^T (f32, 64x64 tiles) ----------------
#define GT 64
#define GKT 64
#define LSTR (GKT + 4)

__global__ __launch_bounds__(256) void gemm_G(const float* __restrict__ x,
                                              const float* __restrict__ y,
                                              float* __restrict__ G) {
    __shared__ float As[GT][LSTR];   // [i][k]
    __shared__ float Bs[GT][LSTR];   // [j][k]
    int bi = blockIdx.y * GT;
    int bj = blockIdx.x * GT;
    int t = threadIdx.x;
    int tx = t & 15, ty = t >> 4;
    float acc[4][4] = {};
    for (int kk = 0; kk < C; kk += GKT) {
        #pragma unroll
        for (int l = 0; l < 4; ++l) {
            int idx = t + l * 256;
            int r = idx >> 4;
            int c4 = idx & 15;
            *(f32x4*)&As[r][c4 * 4] =
                *(const f32x4*)(x + (size_t)(bi + r) * C + kk + c4 * 4);
            *(f32x4*)&Bs[r][c4 * 4] =
                *(const f32x4*)(y + (size_t)(bj + r) * C + kk + c4 * 4);
        }
        __syncthreads();
        #pragma unroll
        for (int k4 = 0; k4 < GKT / 4; ++k4) {
            f32x4 a[4], b[4];
            #pragma unroll
            for (int ii = 0; ii < 4; ++ii)
                a[ii] = *(const f32x4*)&As[ty * 4 + ii][k4 * 4];
            #pragma unroll
            for (int jj = 0; jj < 4; ++jj)
                b[jj] = *(const f32x4*)&Bs[tx + 16 * jj][k4 * 4];
            #pragma unroll
            for (int ii = 0; ii < 4; ++ii)
                #pragma unroll
                for (int jj = 0; jj < 4; ++jj) {
                    acc[ii][jj] = fmaf(a[ii].x, b[jj].x, acc[ii][jj]);
                    acc[ii][jj] = fmaf(a[ii].y, b[jj].y, acc[ii][jj]);
                    acc[ii][jj] = fmaf(a[ii].z, b[jj].z, acc[ii][jj]);
                    acc[ii][jj] = fmaf(a[ii].w, b[jj].w, acc[ii][jj]);
                }
        }
        __syncthreads();
    }
    #pragma unroll
    for (int ii = 0; ii < 4; ++ii) {
        int gi = bi + ty * 4 + ii;
        #pragma unroll
        for (int jj = 0; jj < 4; ++jj)
            G[(size_t)gi * B + bj + tx + 16 * jj] = 2.0f * acc[ii][jj];
    }
}

// ---------------- row pass: U[i] = -LSE_j(G[i][j] + V[j]) ----------------
// 8192 blocks ascending i -> ~64 MiB sliding window moving upward.
__global__ __launch_bounds__(256) void row_lse(const float* __restrict__ G) {
    int i = blockIdx.x;
    int t = threadIdx.x;
    const f32x4* g = (const f32x4*)(G + (size_t)i * B);
    const f32x4* v4 = (const f32x4*)g_V;
    float m = -INFINITY, s = 0.0f;
    #pragma unroll
    for (int it = 0; it < B / 1024; ++it) {   // 8 iterations
        int idx = it * 256 + t;
        f32x4 gv = g[idx];
        f32x4 vv = v4[idx];
        float vals[4] = {gv.x + vv.x, gv.y + vv.y, gv.z + vv.z, gv.w + vv.w};
        #pragma unroll
        for (int k = 0; k < 4; ++k) {
            float val = vals[k];
            float m2 = fmaxf(m, val);
            s = s * __expf(m - m2) + __expf(val - m2);
            m = m2;
        }
    }
    __shared__ float sm[256], ss[256];
    sm[t] = m; ss[t] = s;
    __syncthreads();
    #pragma unroll
    for (int off = 128; off; off >>= 1) {
        if (t < off) {
            float mo = sm[t + off], so = ss[t + off];
            float m1 = sm[t],       s1 = ss[t];
            float m2 = fmaxf(m1, mo);
            ss[t] = s1 * __expf(m1 - m2) + so * __expf(mo - m2);
            sm[t] = m2;
        }
        __syncthreads();
    }
    if (t == 0) g_U[i] = -(sm[0] + logf(ss[0]));
}

// ------- column pass (partials): per (chunk, j): online LSE over 32 rows -------
// 1D grid 8192 blocks: jb = low 5 bits (fast), chunk group DESCENDING in the
// high bits -> resident window ~64 MiB sweeping high rows -> low rows,
// mirror-image of row pass (palindromic LRU schedule over G).
__global__ __launch_bounds__(256) void col_partial(const float* __restrict__ G) {
    int t = threadIdx.x;
    int bx = blockIdx.x;
    int jb = bx & 31;
    int corder = bx >> 5;                 // 0..255 in dispatch order
    int chunk = (CHUNKS - 1) - corder;    // descending rows
    int j = jb * 256 + t;
    int i0 = chunk * RPC;
    __shared__ float Us[RPC];
    if (t < RPC) Us[t] = g_U[i0 + t];
    __syncthreads();
    float m = -INFINITY, s = 0.0f;
    const float* gp = G + (size_t)i0 * B + j;
    #pragma unroll
    for (int r = RPC - 1; r >= 0; --r) {  // descending rows within chunk
        float val = gp[(size_t)r * B] + Us[r];
        float m2 = fmaxf(m, val);
        s = s * __expf(m - m2) + __expf(val - m2);
        m = m2;
    }
    g_pm[chunk * B + j] = m;
    g_ps[chunk * B + j] = s;
}

// ---------------- column combine: V[j] = -(LSE of 256 partials) ----------------
__global__ __launch_bounds__(256) void col_combine() {
    int j = blockIdx.x * 256 + threadIdx.x;
    float m = -INFINITY, s = 0.0f;
    for (int c = 0; c < CHUNKS; ++c) {
        float mc = g_pm[c * B + j], sc = g_ps[c * B + j];
        float m2 = fmaxf(m, mc);
        s = s * __expf(m - m2) + sc * __expf(mc - m2);
        m = m2;
    }
    g_V[j] = -(m + logf(s));
}

// ---------------- argmax + gather: out[i] = y[argmax_j(G[i][j]+V[j])] ----------------
__global__ __launch_bounds__(256) void argmax_out(const float* __restrict__ G,
                                                  const float* __restrict__ y,
                                                  float* __restrict__ out) {
    int i = blockIdx.x;   // ascending: palindrome continues after descending col
    int t = threadIdx.x;
    const f32x4* g = (const f32x4*)(G + (size_t)i * B);
    const f32x4* v4 = (const f32x4*)g_V;
    float best = -INFINITY;
    int bj = B;
    #pragma unroll
    for (int it = 0; it < B / 1024; ++it) {
        int idx = it * 256 + t;
        f32x4 gv = g[idx];
        f32x4 vv = v4[idx];
        float vals[4] = {gv.x + vv.x, gv.y + vv.y, gv.z + vv.z, gv.w + vv.w};
        #pragma unroll
        for (int k = 0; k < 4; ++k) {
            int j = idx * 4 + k;
            if (vals[k] > best) { best = vals[k]; bj = j; }
        }
    }
    __shared__ float bm[256];
    __shared__ int   bidx[256];
    bm[t] = best; bidx[t] = bj;
    __syncthreads();
    #pragma unroll
    for (int off = 128; off; off >>= 1) {
        if (t < off) {
            float om = bm[t + off]; int oj = bidx[t + off];
            if (om > bm[t] || (om == bm[t] && oj < bidx[t])) { bm[t] = om; bidx[t] = oj; }
        }
        __syncthreads();
    }
    int jstar = bidx[0];
    out[(size_t)i * C + t] = y[(size_t)jstar * C + t];
}

extern "C" void kernel_launch(void* const* d_in, const int* in_sizes, int n_in,
                              void* d_out, int out_size, void* d_ws, size_t ws_size,
                              hipStream_t stream) {
    const float* x = (const float*)d_in[0];
    const float* y = (const float*)d_in[1];
    float* out = (float*)d_out;
    float* G = (float*)d_ws;     // exactly 256 MiB

    init_V<<<B / 4, 256, 0, stream>>>(y);
    gemm_G<<<dim3(B / GT, B / GT), 256, 0, stream>>>(x, y, G);
    for (int l = 0; l < LITERS; ++l) {
        row_lse<<<B, 256, 0, stream>>>(G);
        col_partial<<<CHUNKS * 32, 256, 0, stream>>>(G);
        col_combine<<<B / 256, 256, 0, stream>>>();
    }
    argmax_out<<<B, 256, 0, stream>>>(G, y, out);
}

// Round 8
// 9326.205 us; speedup vs baseline: 1.1800x; 1.1800x over previous
//
#include <hip/hip_runtime.h>
#include <math.h>

// Sinkhorn OT layer, B=8192, C=256, L=100, LAMBD=1.
//
// U = log_u - ||x_i||^2, V = log_v - ||y_j||^2, G[i][j] = 2*dot(x_i,y_j):
//   U[i] = -LSE_j(G[i][j] + V[j]),  V[j] = -LSE_i(G[i][j] + U[i])
// init V[j] = -||y_j||^2. Final: out[i] = y[argmax_j(G[i][j]+V[j])].
//
// d_ws: G only (256 MiB exactly). Small state in __device__ globals, plain
// loads/stores; cross-dispatch visibility via kernel boundaries.
//
// Evidence ledger:
//  R4: non-temporal hints regress (forfeit L2/L3) -> none used.
//  R5: agent-scope ACQ_REL fused combine regresses (~25 us/iter) -> separate
//      col_combine kernel.
//  R6: iteration phase = 6.32 TB/s effective == copy ceiling. 9.16 ms.
//  R7: genuine sliding-window col pass (RPC=32) REGRESSED (11.0 ms) ->
//      MALL scheduling cannot beat the ~6.3 TB/s fabric cap; 2 f32 scans of
//      G per iteration is the structural floor (~8.13 ms).
//  R8 (this): exact R6 iteration structure + 128x128/8x8 GEMM (LDS
//      bytes/FLOP halved: 546 -> ~340 us predicted).

#define B 8192
#define C 256
#define LITERS 100
#define CHUNKS 32
#define RPC 256                    // rows per column-pass chunk

typedef float f32x4 __attribute__((ext_vector_type(4)));

__device__ __align__(16) float g_U[B];
__device__ __align__(16) float g_V[B];
__device__ __align__(16) float g_pm[CHUNKS * B];
__device__ __align__(16) float g_ps[CHUNKS * B];

// ---------------- init: V[j] = -||y_j||^2 ----------------
__global__ __launch_bounds__(256) void init_V(const float* __restrict__ y) {
    int wave = threadIdx.x >> 6;
    int lane = threadIdx.x & 63;
    int row = blockIdx.x * 4 + wave;
    const f32x4* yr = (const f32x4*)(y + (size_t)row * C);
    f32x4 v = yr[lane];
    float s = v.x * v.x + v.y * v.y + v.z * v.z + v.w * v.w;
    #pragma unroll
    for (int off = 32; off; off >>= 1) s += __shfl_down(s, off, 64);
    if (lane == 0) g_V[row] = -s;
}

// ---------------- GEMM: G = 2 * x @ y^T (f32, 128x128 tiles, 8x8/thread) ----
// LDS [row][k] layout, stride 36 (== 4 mod 32: verified conflict-free
// residue from R6). A-rows ty+16*ii, B-rows tx+16*jj (interleaved) keep all
// fragment reads 2-way-or-broadcast (free).
#define GT 128
#define BK 32
#define LSTR (BK + 4)   // 36 floats

__global__ __launch_bounds__(256) void gemm_G(const float* __restrict__ x,
                                              const float* __restrict__ y,
                                              float* __restrict__ G) {
    __shared__ float As[GT][LSTR];   // [i][k]  18 KiB
    __shared__ float Bs[GT][LSTR];   // [j][k]  18 KiB
    int bi = blockIdx.y * GT;
    int bj = blockIdx.x * GT;
    int t = threadIdx.x;
    int tx = t & 15, ty = t >> 4;
    float acc[8][8] = {};
    for (int kk = 0; kk < C; kk += BK) {
        // stage 128 rows x 32 k of each matrix: 1024 float4, 4 per thread
        #pragma unroll
        for (int l = 0; l < 4; ++l) {
            int idx = t + l * 256;         // 0..1023
            int r = idx >> 3;              // row 0..127
            int c4 = idx & 7;              // float4 col 0..7
            *(f32x4*)&As[r][c4 * 4] =
                *(const f32x4*)(x + (size_t)(bi + r) * C + kk + c4 * 4);
            *(f32x4*)&Bs[r][c4 * 4] =
                *(const f32x4*)(y + (size_t)(bj + r) * C + kk + c4 * 4);
        }
        __syncthreads();
        #pragma unroll
        for (int k4 = 0; k4 < BK / 4; ++k4) {
            f32x4 a[8], b[8];
            #pragma unroll
            for (int ii = 0; ii < 8; ++ii)
                a[ii] = *(const f32x4*)&As[ty + 16 * ii][k4 * 4];
            #pragma unroll
            for (int jj = 0; jj < 8; ++jj)
                b[jj] = *(const f32x4*)&Bs[tx + 16 * jj][k4 * 4];
            #pragma unroll
            for (int ii = 0; ii < 8; ++ii)
                #pragma unroll
                for (int jj = 0; jj < 8; ++jj) {
                    acc[ii][jj] = fmaf(a[ii].x, b[jj].x, acc[ii][jj]);
                    acc[ii][jj] = fmaf(a[ii].y, b[jj].y, acc[ii][jj]);
                    acc[ii][jj] = fmaf(a[ii].z, b[jj].z, acc[ii][jj]);
                    acc[ii][jj] = fmaf(a[ii].w, b[jj].w, acc[ii][jj]);
                }
        }
        __syncthreads();
    }
    #pragma unroll
    for (int ii = 0; ii < 8; ++ii) {
        int gi = bi + ty + 16 * ii;
        #pragma unroll
        for (int jj = 0; jj < 8; ++jj)
            G[(size_t)gi * B + bj + tx + 16 * jj] = 2.0f * acc[ii][jj];
    }
}

// ---------------- row pass: U[i] = -LSE_j(G[i][j] + V[j]) ----------------
__global__ __launch_bounds__(256) void row_lse(const float* __restrict__ G) {
    int i = blockIdx.x;                     // ascending rows
    int t = threadIdx.x;
    const f32x4* g = (const f32x4*)(G + (size_t)i * B);
    const f32x4* v4 = (const f32x4*)g_V;
    float m = -INFINITY, s = 0.0f;
    #pragma unroll
    for (int it = 0; it < B / 1024; ++it) {   // 8 iterations
        int idx = it * 256 + t;
        f32x4 gv = g[idx];
        f32x4 vv = v4[idx];
        float vals[4] = {gv.x + vv.x, gv.y + vv.y, gv.z + vv.z, gv.w + vv.w};
        #pragma unroll
        for (int k = 0; k < 4; ++k) {
            float val = vals[k];
            float m2 = fmaxf(m, val);
            s = s * __expf(m - m2) + __expf(val - m2);
            m = m2;
        }
    }
    __shared__ float sm[256], ss[256];
    sm[t] = m; ss[t] = s;
    __syncthreads();
    #pragma unroll
    for (int off = 128; off; off >>= 1) {
        if (t < off) {
            float mo = sm[t + off], so = ss[t + off];
            float m1 = sm[t],       s1 = ss[t];
            float m2 = fmaxf(m1, mo);
            ss[t] = s1 * __expf(m1 - m2) + so * __expf(mo - m2);
            sm[t] = m2;
        }
        __syncthreads();
    }
    if (t == 0) g_U[i] = -(sm[0] + logf(ss[0]));
}

// ------- column pass (partials): per (chunk, j): online LSE over 256 rows -------
// Zigzag: chunks and within-chunk rows walk DESCENDING (R6 structure).
__global__ __launch_bounds__(256) void col_partial(const float* __restrict__ G) {
    int t = threadIdx.x;
    int j = blockIdx.x * 256 + t;
    int chunk = (CHUNKS - 1) - blockIdx.y;
    int i0 = chunk * RPC;
    __shared__ float Us[RPC];
    Us[t] = g_U[i0 + t];
    __syncthreads();
    float m = -INFINITY, s = 0.0f;
    const float* gp = G + (size_t)i0 * B + j;
    #pragma unroll 8
    for (int r = RPC - 1; r >= 0; --r) {      // descending rows
        float val = gp[(size_t)r * B] + Us[r];
        float m2 = fmaxf(m, val);
        s = s * __expf(m - m2) + __expf(val - m2);
        m = m2;
    }
    g_pm[chunk * B + j] = m;
    g_ps[chunk * B + j] = s;
}

// ---------------- column combine: V[j] = -(LSE of 32 partials) ----------------
__global__ __launch_bounds__(256) void col_combine() {
    int j = blockIdx.x * 256 + threadIdx.x;
    float m = -INFINITY, s = 0.0f;
    #pragma unroll
    for (int c = 0; c < CHUNKS; ++c) {
        float mc = g_pm[c * B + j], sc = g_ps[c * B + j];
        float m2 = fmaxf(m, mc);
        s = s * __expf(m - m2) + sc * __expf(mc - m2);
        m = m2;
    }
    g_V[j] = -(m + logf(s));
}

// ---------------- argmax + gather: out[i] = y[argmax_j(G[i][j]+V[j])] ----------------
__global__ __launch_bounds__(256) void argmax_out(const float* __restrict__ G,
                                                  const float* __restrict__ y,
                                                  float* __restrict__ out) {
    int i = blockIdx.x;
    int t = threadIdx.x;
    const f32x4* g = (const f32x4*)(G + (size_t)i * B);
    const f32x4* v4 = (const f32x4*)g_V;
    float best = -INFINITY;
    int bj = B;
    #pragma unroll
    for (int it = 0; it < B / 1024; ++it) {
        int idx = it * 256 + t;
        f32x4 gv = g[idx];
        f32x4 vv = v4[idx];
        float vals[4] = {gv.x + vv.x, gv.y + vv.y, gv.z + vv.z, gv.w + vv.w};
        #pragma unroll
        for (int k = 0; k < 4; ++k) {
            int j = idx * 4 + k;
            if (vals[k] > best) { best = vals[k]; bj = j; }
        }
    }
    __shared__ float bm[256];
    __shared__ int   bidx[256];
    bm[t] = best; bidx[t] = bj;
    __syncthreads();
    #pragma unroll
    for (int off = 128; off; off >>= 1) {
        if (t < off) {
            float om = bm[t + off]; int oj = bidx[t + off];
            if (om > bm[t] || (om == bm[t] && oj < bidx[t])) { bm[t] = om; bidx[t] = oj; }
        }
        __syncthreads();
    }
    int jstar = bidx[0];
    out[(size_t)i * C + t] = y[(size_t)jstar * C + t];
}

extern "C" void kernel_launch(void* const* d_in, const int* in_sizes, int n_in,
                              void* d_out, int out_size, void* d_ws, size_t ws_size,
                              hipStream_t stream) {
    const float* x = (const float*)d_in[0];
    const float* y = (const float*)d_in[1];
    float* out = (float*)d_out;
    float* G = (float*)d_ws;     // exactly 256 MiB

    init_V<<<B / 4, 256, 0, stream>>>(y);
    gemm_G<<<dim3(B / GT, B / GT), 256, 0, stream>>>(x, y, G);
    for (int l = 0; l < LITERS; ++l) {
        row_lse<<<B, 256, 0, stream>>>(G);
        col_partial<<<dim3(B / 256, CHUNKS), 256, 0, stream>>>(G);
        col_combine<<<B / 256, 256, 0, stream>>>();
    }
    argmax_out<<<B, 256, 0, stream>>>(G, y, out);
}

// Round 9
// 9267.516 us; speedup vs baseline: 1.1875x; 1.0063x over previous
//
#include <hip/hip_runtime.h>
#include <math.h>

// Sinkhorn OT layer, B=8192, C=256, L=100, LAMBD=1.
//
// U = log_u - ||x_i||^2, V = log_v - ||y_j||^2, G[i][j] = 2*dot(x_i,y_j):
//   U[i] = -LSE_j(G[i][j] + V[j]),  V[j] = -LSE_i(G[i][j] + U[i])
// init V[j] = -||y_j||^2. Final: out[i] = y[argmax_j(G[i][j]+V[j])].
//
// d_ws: G only (256 MiB exactly). Small state in __device__ globals, plain
// loads/stores; cross-dispatch visibility via kernel boundaries.
//
// Evidence ledger (best = R6 config, reproduced here):
//  R4: non-temporal hints regress (forfeit L2/L3 service) -> none used.
//  R5: agent-scope ACQ_REL fused combine regresses ~25 us/iter -> separate
//      col_combine kernel, plain stores.
//  R6: THIS config: 9164 us. Iteration = 84.9 us/iter == 2x268.4MB @ 6.3TB/s
//      copy ceiling (100% of achievable BW). GEMM 546 us, 0 LDS conflicts.
//  R7: sliding-window col pass regressed (MALL can't beat fabric cap).
//  R8: 128x128/8x8 GEMM regressed (~700 us; VGPR pressure) -> reverted.
// Remaining headroom: ~350 us locked in f32 vector GEMM (219 us VALU floor);
// two structured attempts failed -> this is the operating point.

#define B 8192
#define C 256
#define LITERS 100
#define CHUNKS 32
#define RPC 256                    // rows per column-pass chunk

typedef float f32x4 __attribute__((ext_vector_type(4)));

__device__ __align__(16) float g_U[B];
__device__ __align__(16) float g_V[B];
__device__ __align__(16) float g_pm[CHUNKS * B];
__device__ __align__(16) float g_ps[CHUNKS * B];

// ---------------- init: V[j] = -||y_j||^2 ----------------
__global__ __launch_bounds__(256) void init_V(const float* __restrict__ y) {
    int wave = threadIdx.x >> 6;
    int lane = threadIdx.x & 63;
    int row = blockIdx.x * 4 + wave;
    const f32x4* yr = (const f32x4*)(y + (size_t)row * C);
    f32x4 v = yr[lane];
    float s = v.x * v.x + v.y * v.y + v.z * v.z + v.w * v.w;
    #pragma unroll
    for (int off = 32; off; off >>= 1) s += __shfl_down(s, off, 64);
    if (lane == 0) g_V[row] = -s;
}

// ---------------- GEMM: G = 2 * x @ y^T (f32, 64x64 tiles) ----------------
// LDS tiles in natural [row][k] layout (no transpose on staging, float4 IO).
// Thread (tx,ty) computes A-rows {ty*4+ii} x B-rows {tx+16*jj}.
#define GT 64
#define GKT 64
#define LSTR (GKT + 4)   // 68 floats; float4-aligned offsets

__global__ __launch_bounds__(256) void gemm_G(const float* __restrict__ x,
                                              const float* __restrict__ y,
                                              float* __restrict__ G) {
    __shared__ float As[GT][LSTR];   // [i][k]
    __shared__ float Bs[GT][LSTR];   // [j][k]
    int bi = blockIdx.y * GT;
    int bj = blockIdx.x * GT;
    int t = threadIdx.x;
    int tx = t & 15, ty = t >> 4;
    float acc[4][4] = {};
    for (int kk = 0; kk < C; kk += GKT) {
        #pragma unroll
        for (int l = 0; l < 4; ++l) {
            int idx = t + l * 256;         // float4 index in tile
            int r = idx >> 4;              // tile row 0..63
            int c4 = idx & 15;             // float4 col 0..15
            *(f32x4*)&As[r][c4 * 4] =
                *(const f32x4*)(x + (size_t)(bi + r) * C + kk + c4 * 4);
            *(f32x4*)&Bs[r][c4 * 4] =
                *(const f32x4*)(y + (size_t)(bj + r) * C + kk + c4 * 4);
        }
        __syncthreads();
        #pragma unroll
        for (int k4 = 0; k4 < GKT / 4; ++k4) {
            f32x4 a[4], b[4];
            #pragma unroll
            for (int ii = 0; ii < 4; ++ii)
                a[ii] = *(const f32x4*)&As[ty * 4 + ii][k4 * 4];
            #pragma unroll
            for (int jj = 0; jj < 4; ++jj)
                b[jj] = *(const f32x4*)&Bs[tx + 16 * jj][k4 * 4];
            #pragma unroll
            for (int ii = 0; ii < 4; ++ii)
                #pragma unroll
                for (int jj = 0; jj < 4; ++jj) {
                    acc[ii][jj] = fmaf(a[ii].x, b[jj].x, acc[ii][jj]);
                    acc[ii][jj] = fmaf(a[ii].y, b[jj].y, acc[ii][jj]);
                    acc[ii][jj] = fmaf(a[ii].z, b[jj].z, acc[ii][jj]);
                    acc[ii][jj] = fmaf(a[ii].w, b[jj].w, acc[ii][jj]);
                }
        }
        __syncthreads();
    }
    #pragma unroll
    for (int ii = 0; ii < 4; ++ii) {
        int gi = bi + ty * 4 + ii;
        #pragma unroll
        for (int jj = 0; jj < 4; ++jj)
            G[(size_t)gi * B + bj + tx + 16 * jj] = 2.0f * acc[ii][jj];
    }
}

// ---------------- row pass: U[i] = -LSE_j(G[i][j] + V[j]) ----------------
__global__ __launch_bounds__(256) void row_lse(const float* __restrict__ G) {
    int i = blockIdx.x;                     // ascending rows
    int t = threadIdx.x;
    const f32x4* g = (const f32x4*)(G + (size_t)i * B);
    const f32x4* v4 = (const f32x4*)g_V;
    float m = -INFINITY, s = 0.0f;
    #pragma unroll
    for (int it = 0; it < B / 1024; ++it) {   // 8 iterations
        int idx = it * 256 + t;
        f32x4 gv = g[idx];
        f32x4 vv = v4[idx];
        float vals[4] = {gv.x + vv.x, gv.y + vv.y, gv.z + vv.z, gv.w + vv.w};
        #pragma unroll
        for (int k = 0; k < 4; ++k) {
            float val = vals[k];
            float m2 = fmaxf(m, val);
            s = s * __expf(m - m2) + __expf(val - m2);
            m = m2;
        }
    }
    __shared__ float sm[256], ss[256];
    sm[t] = m; ss[t] = s;
    __syncthreads();
    #pragma unroll
    for (int off = 128; off; off >>= 1) {
        if (t < off) {
            float mo = sm[t + off], so = ss[t + off];
            float m1 = sm[t],       s1 = ss[t];
            float m2 = fmaxf(m1, mo);
            ss[t] = s1 * __expf(m1 - m2) + so * __expf(mo - m2);
            sm[t] = m2;
        }
        __syncthreads();
    }
    if (t == 0) g_U[i] = -(sm[0] + logf(ss[0]));
}

// ------- column pass (partials): per (chunk, j): online LSE over 256 rows -------
// Zigzag: chunks and within-chunk rows walk DESCENDING so this pass starts
// on the rows row_lse touched last.
__global__ __launch_bounds__(256) void col_partial(const float* __restrict__ G) {
    int t = threadIdx.x;
    int j = blockIdx.x * 256 + t;
    int chunk = (CHUNKS - 1) - blockIdx.y;
    int i0 = chunk * RPC;
    __shared__ float Us[RPC];
    Us[t] = g_U[i0 + t];
    __syncthreads();
    float m = -INFINITY, s = 0.0f;
    const float* gp = G + (size_t)i0 * B + j;
    #pragma unroll 8
    for (int r = RPC - 1; r >= 0; --r) {      // descending rows
        float val = gp[(size_t)r * B] + Us[r];
        float m2 = fmaxf(m, val);
        s = s * __expf(m - m2) + __expf(val - m2);
        m = m2;
    }
    g_pm[chunk * B + j] = m;
    g_ps[chunk * B + j] = s;
}

// ---------------- column combine: V[j] = -(LSE of 32 partials) ----------------
__global__ __launch_bounds__(256) void col_combine() {
    int j = blockIdx.x * 256 + threadIdx.x;
    float m = -INFINITY, s = 0.0f;
    #pragma unroll
    for (int c = 0; c < CHUNKS; ++c) {
        float mc = g_pm[c * B + j], sc = g_ps[c * B + j];
        float m2 = fmaxf(m, mc);
        s = s * __expf(m - m2) + sc * __expf(mc - m2);
        m = m2;
    }
    g_V[j] = -(m + logf(s));
}

// ---------------- argmax + gather: out[i] = y[argmax_j(G[i][j]+V[j])] ----------------
__global__ __launch_bounds__(256) void argmax_out(const float* __restrict__ G,
                                                  const float* __restrict__ y,
                                                  float* __restrict__ out) {
    int i = blockIdx.x;
    int t = threadIdx.x;
    const f32x4* g = (const f32x4*)(G + (size_t)i * B);
    const f32x4* v4 = (const f32x4*)g_V;
    float best = -INFINITY;
    int bj = B;
    #pragma unroll
    for (int it = 0; it < B / 1024; ++it) {
        int idx = it * 256 + t;
        f32x4 gv = g[idx];
        f32x4 vv = v4[idx];
        float vals[4] = {gv.x + vv.x, gv.y + vv.y, gv.z + vv.z, gv.w + vv.w};
        #pragma unroll
        for (int k = 0; k < 4; ++k) {
            int j = idx * 4 + k;
            if (vals[k] > best) { best = vals[k]; bj = j; }
        }
    }
    __shared__ float bm[256];
    __shared__ int   bidx[256];
    bm[t] = best; bidx[t] = bj;
    __syncthreads();
    #pragma unroll
    for (int off = 128; off; off >>= 1) {
        if (t < off) {
            float om = bm[t + off]; int oj = bidx[t + off];
            if (om > bm[t] || (om == bm[t] && oj < bidx[t])) { bm[t] = om; bidx[t] = oj; }
        }
        __syncthreads();
    }
    int jstar = bidx[0];
    out[(size_t)i * C + t] = y[(size_t)jstar * C + t];
}

extern "C" void kernel_launch(void* const* d_in, const int* in_sizes, int n_in,
                              void* d_out, int out_size, void* d_ws, size_t ws_size,
                              hipStream_t stream) {
    const float* x = (const float*)d_in[0];
    const float* y = (const float*)d_in[1];
    float* out = (float*)d_out;
    float* G = (float*)d_ws;     // exactly 256 MiB

    init_V<<<B / 4, 256, 0, stream>>>(y);
    gemm_G<<<dim3(B / GT, B / GT), 256, 0, stream>>>(x, y, G);
    for (int l = 0; l < LITERS; ++l) {
        row_lse<<<B, 256, 0, stream>>>(G);
        col_partial<<<dim3(B / 256, CHUNKS), 256, 0, stream>>>(G);
        col_combine<<<B / 256, 256, 0, stream>>>();
    }
    argmax_out<<<B, 256, 0, stream>>>(G, y, out);
}